// Round 1
// baseline (421.910 us; speedup 1.0000x reference)
//
#include <hip/hip_runtime.h>

typedef __bf16 bf16;
typedef __bf16 bf16x8 __attribute__((ext_vector_type(8)));
typedef __bf16 bf16x4 __attribute__((ext_vector_type(4)));
typedef float f32x4 __attribute__((ext_vector_type(4)));

#define LOG2E 1.44269504f

__device__ __forceinline__ void gload_lds16(const void* g, void* l) {
  __builtin_amdgcn_global_load_lds(
      (const __attribute__((address_space(1))) unsigned int*)g,
      (__attribute__((address_space(3))) unsigned int*)l, 16, 0, 0);
}

// ---------------- transpose + cast: src fp32 [R][C] -> dst bf16 [C][R] ----------------
__global__ __launch_bounds__(256) void transpose_cast(const float* __restrict__ src,
                                                      bf16* __restrict__ dst,
                                                      int R, int C) {
  __shared__ float tile[32][33];
  const int tx = threadIdx.x & 31, ty = threadIdx.x >> 5;  // 32 x 8
  const int c0 = blockIdx.x * 32, r0 = blockIdx.y * 32;
#pragma unroll
  for (int i = 0; i < 4; i++)
    tile[ty + i * 8][tx] = src[(size_t)(r0 + ty + i * 8) * C + c0 + tx];
  __syncthreads();
#pragma unroll
  for (int i = 0; i < 4; i++)
    dst[(size_t)(c0 + ty + i * 8) * R + r0 + tx] = (bf16)tile[tx][ty + i * 8];
}

// ---------------- LayerNorm: fp32 [rows][1024] -> bf16, 1 wave per row ----------------
__global__ __launch_bounds__(256) void ln_kernel(const float* __restrict__ x,
                                                 const float* __restrict__ g,
                                                 const float* __restrict__ b,
                                                 bf16* __restrict__ y) {
  const int w = threadIdx.x >> 6, lane = threadIdx.x & 63;
  const int row = blockIdx.x * 4 + w;
  const float* xr = x + (size_t)row * 1024;
  float4 v[4];
  float s = 0.f, sq = 0.f;
#pragma unroll
  for (int c = 0; c < 4; c++) {
    v[c] = *reinterpret_cast<const float4*>(xr + c * 256 + lane * 4);
    s += v[c].x + v[c].y + v[c].z + v[c].w;
    sq += v[c].x * v[c].x + v[c].y * v[c].y + v[c].z * v[c].z + v[c].w * v[c].w;
  }
#pragma unroll
  for (int d = 32; d >= 1; d >>= 1) {
    s += __shfl_xor(s, d, 64);
    sq += __shfl_xor(sq, d, 64);
  }
  const float mu = s * (1.f / 1024.f);
  const float rs = rsqrtf(sq * (1.f / 1024.f) - mu * mu + 1e-6f);
#pragma unroll
  for (int c = 0; c < 4; c++) {
    float4 gv = *reinterpret_cast<const float4*>(g + c * 256 + lane * 4);
    float4 bv = *reinterpret_cast<const float4*>(b + c * 256 + lane * 4);
    bf16x4 ov;
    ov[0] = (bf16)((v[c].x - mu) * rs * gv.x + bv.x);
    ov[1] = (bf16)((v[c].y - mu) * rs * gv.y + bv.y);
    ov[2] = (bf16)((v[c].z - mu) * rs * gv.z + bv.z);
    ov[3] = (bf16)((v[c].w - mu) * rs * gv.w + bv.w);
    *reinterpret_cast<bf16x4*>(y + (size_t)row * 1024 + c * 256 + lane * 4) = ov;
  }
}

// ---------------- GEMM: C[M][N] = A[M][K] @ Bt[N][K]^T, bf16 in, fp32 acc --------------
// EPI 0: store bf16
// EPI 1: store fp32 = acc + (bias?bias[col]:0) + res[idx]
// EPI 2: store bf16 = relu(acc + bias[col])
template <int EPI>
__global__ __launch_bounds__(256) void gemm_bt(const bf16* __restrict__ A,
                                               const bf16* __restrict__ Bt,
                                               void* __restrict__ Cout,
                                               const float* __restrict__ bias,
                                               const float* __restrict__ res,
                                               int M, int N, int K) {
  __shared__ __align__(16) bf16 As[128][32];
  __shared__ __align__(16) bf16 Bs[128][32];
  const int tid = threadIdx.x;
  const int w = tid >> 6, lane = tid & 63;
  const int wr = w >> 1, wc = w & 1;
  const int bm = blockIdx.x * 128, bn = blockIdx.y * 128;

  f32x4 acc[4][4] = {};
  const int r4 = lane >> 2;        // 0..15
  const int c8 = (lane & 3) * 8;   // k offset within 32
  const bf16* Ag = A + (size_t)(bm + w * 32 + r4) * K + c8;
  const bf16* Bg = Bt + (size_t)(bn + w * 32 + r4) * K + c8;
  const int fr = lane & 15, fo = (lane >> 4) * 8;

  for (int k0 = 0; k0 < K; k0 += 32) {
    gload_lds16(Ag + k0, &As[w * 32][0]);
    gload_lds16(Ag + (size_t)16 * K + k0, &As[w * 32 + 16][0]);
    gload_lds16(Bg + k0, &Bs[w * 32][0]);
    gload_lds16(Bg + (size_t)16 * K + k0, &Bs[w * 32 + 16][0]);
    __syncthreads();
    bf16x8 af[4], bfr[4];
#pragma unroll
    for (int m = 0; m < 4; m++) af[m] = *reinterpret_cast<const bf16x8*>(&As[wr * 64 + m * 16 + fr][fo]);
#pragma unroll
    for (int n = 0; n < 4; n++) bfr[n] = *reinterpret_cast<const bf16x8*>(&Bs[wc * 64 + n * 16 + fr][fo]);
#pragma unroll
    for (int m = 0; m < 4; m++)
#pragma unroll
      for (int n = 0; n < 4; n++)
        acc[m][n] = __builtin_amdgcn_mfma_f32_16x16x32_bf16(af[m], bfr[n], acc[m][n], 0, 0, 0);
    __syncthreads();
  }

  const int cr = (lane >> 4) * 4, cc = lane & 15;
#pragma unroll
  for (int m = 0; m < 4; m++) {
#pragma unroll
    for (int n = 0; n < 4; n++) {
      const int row = bm + wr * 64 + m * 16 + cr;
      const int col = bn + wc * 64 + n * 16 + cc;
#pragma unroll
      for (int r = 0; r < 4; r++) {
        const float va = acc[m][n][r];
        const size_t idx = (size_t)(row + r) * N + col;
        if (EPI == 0) {
          ((bf16*)Cout)[idx] = (bf16)va;
        } else if (EPI == 1) {
          ((float*)Cout)[idx] = va + (bias ? bias[col] : 0.f) + res[idx];
        } else {
          const float t = va + bias[col];
          ((bf16*)Cout)[idx] = (bf16)(t > 0.f ? t : 0.f);
        }
      }
    }
  }
}

// ---------------- Flash attention: [B,S,H,Dk] bf16 Q,K,V -> O bf16 --------------------
// grid: (S/64, B*H); block 256 (4 waves); wave handles 16 q rows; K-tile = 32 keys
__global__ __launch_bounds__(256) void attn_kernel(const bf16* __restrict__ Q,
                                                   const bf16* __restrict__ Kb,
                                                   const bf16* __restrict__ Vb,
                                                   bf16* __restrict__ O) {
  __shared__ __align__(16) bf16 Kt[32][64];
  __shared__ __align__(16) bf16 Vt[64][32];
  __shared__ __align__(16) bf16 Pb[4][16][32];
  const int tid = threadIdx.x, w = tid >> 6, lane = tid & 63;
  const int bh = blockIdx.y;
  const int b = bh >> 4, h = bh & 15;
  const int q0 = blockIdx.x * 64 + w * 16;
  const size_t base = (size_t)b * 1024 * 1024 + h * 64;  // element offset; row s -> + s*1024
  const int fr = lane & 15, fo = (lane >> 4) * 8;

  bf16x8 qf[2];
#pragma unroll
  for (int kk = 0; kk < 2; kk++)
    qf[kk] = *reinterpret_cast<const bf16x8*>(Q + base + (size_t)(q0 + fr) * 1024 + kk * 32 + fo);

  float m[4], l[4];
  f32x4 o[4] = {};
#pragma unroll
  for (int r = 0; r < 4; r++) { m[r] = -1e30f; l[r] = 0.f; }

  const int skey = tid >> 3;       // 0..31
  const int sd = (tid & 7) * 8;    // 0..56

  for (int kt = 0; kt < 32; kt++) {
    const int krow = kt * 32 + skey;
    gload_lds16(Kb + base + (size_t)krow * 1024 + sd, &Kt[w * 8][0]);
    bf16x8 vv = *reinterpret_cast<const bf16x8*>(Vb + base + (size_t)krow * 1024 + sd);
#pragma unroll
    for (int j = 0; j < 8; j++) Vt[sd + j][skey] = vv[j];
    __syncthreads();

    // S = (Q K^T) / 8
    f32x4 s[2] = {};
#pragma unroll
    for (int nt = 0; nt < 2; nt++) {
      bf16x8 k0f = *reinterpret_cast<const bf16x8*>(&Kt[nt * 16 + fr][fo]);
      bf16x8 k1f = *reinterpret_cast<const bf16x8*>(&Kt[nt * 16 + fr][32 + fo]);
      s[nt] = __builtin_amdgcn_mfma_f32_16x16x32_bf16(qf[0], k0f, s[nt], 0, 0, 0);
      s[nt] = __builtin_amdgcn_mfma_f32_16x16x32_bf16(qf[1], k1f, s[nt], 0, 0, 0);
    }
#pragma unroll
    for (int nt = 0; nt < 2; nt++)
#pragma unroll
      for (int r = 0; r < 4; r++) s[nt][r] *= 0.125f;

    // online softmax
    float rmax[4], rsum[4], sc[4], p0[4], p1[4];
#pragma unroll
    for (int r = 0; r < 4; r++) rmax[r] = fmaxf(s[0][r], s[1][r]);
#pragma unroll
    for (int d = 1; d < 16; d <<= 1)
#pragma unroll
      for (int r = 0; r < 4; r++) rmax[r] = fmaxf(rmax[r], __shfl_xor(rmax[r], d, 64));
#pragma unroll
    for (int r = 0; r < 4; r++) {
      const float mn = fmaxf(m[r], rmax[r]);
      sc[r] = exp2f((m[r] - mn) * LOG2E);
      p0[r] = exp2f((s[0][r] - mn) * LOG2E);
      p1[r] = exp2f((s[1][r] - mn) * LOG2E);
      m[r] = mn;
      rsum[r] = p0[r] + p1[r];
    }
#pragma unroll
    for (int d = 1; d < 16; d <<= 1)
#pragma unroll
      for (int r = 0; r < 4; r++) rsum[r] += __shfl_xor(rsum[r], d, 64);
#pragma unroll
    for (int r = 0; r < 4; r++) l[r] = l[r] * sc[r] + rsum[r];
#pragma unroll
    for (int nt = 0; nt < 4; nt++)
#pragma unroll
      for (int r = 0; r < 4; r++) o[nt][r] *= sc[r];

    // P -> LDS (per-wave private), then PV
    const int pr = (lane >> 4) * 4;
#pragma unroll
    for (int r = 0; r < 4; r++) {
      Pb[w][pr + r][fr] = (bf16)p0[r];
      Pb[w][pr + r][16 + fr] = (bf16)p1[r];
    }
    bf16x8 pa = *reinterpret_cast<const bf16x8*>(&Pb[w][fr][fo]);
#pragma unroll
    for (int nt = 0; nt < 4; nt++) {
      bf16x8 vf = *reinterpret_cast<const bf16x8*>(&Vt[nt * 16 + fr][fo]);
      o[nt] = __builtin_amdgcn_mfma_f32_16x16x32_bf16(pa, vf, o[nt], 0, 0, 0);
    }
    __syncthreads();
  }

  const int pr = (lane >> 4) * 4;
  float rl[4];
#pragma unroll
  for (int r = 0; r < 4; r++) rl[r] = 1.f / l[r];
#pragma unroll
  for (int nt = 0; nt < 4; nt++)
#pragma unroll
    for (int r = 0; r < 4; r++)
      O[base + (size_t)(q0 + pr + r) * 1024 + nt * 16 + fr] = (bf16)(o[nt][r] * rl[r]);
}

// --------------------------------- launch -------------------------------------------
extern "C" void kernel_launch(void* const* d_in, const int* in_sizes, int n_in,
                              void* d_out, int out_size, void* d_ws, size_t ws_size,
                              hipStream_t stream) {
  const float* x     = (const float*)d_in[0];
  const float* ln1_g = (const float*)d_in[1];
  const float* ln1_b = (const float*)d_in[2];
  const float* wq    = (const float*)d_in[3];
  const float* wk    = (const float*)d_in[4];
  const float* wv    = (const float*)d_in[5];
  const float* wo    = (const float*)d_in[6];
  const float* ln2_g = (const float*)d_in[7];
  const float* ln2_b = (const float*)d_in[8];
  const float* w1    = (const float*)d_in[9];
  const float* b1    = (const float*)d_in[10];
  const float* w2    = (const float*)d_in[11];
  const float* b2    = (const float*)d_in[12];

  const size_t MB = 1ull << 20;
  char* ws = (char*)d_ws;
  bf16* wTq = (bf16*)(ws + 0 * MB);
  bf16* wTk = (bf16*)(ws + 2 * MB);
  bf16* wTv = (bf16*)(ws + 4 * MB);
  bf16* wTo = (bf16*)(ws + 6 * MB);
  bf16* wT1 = (bf16*)(ws + 8 * MB);    // 8MB
  bf16* wT2 = (bf16*)(ws + 16 * MB);   // 8MB
  bf16* x1  = (bf16*)(ws + 24 * MB);   // 8MB; attn output aliases this slot later
  bf16* Qb  = (bf16*)(ws + 32 * MB);   // 8MB; x2 aliases later
  bf16* Kb  = (bf16*)(ws + 40 * MB);
  bf16* Vb  = (bf16*)(ws + 48 * MB);
  float* xres = (float*)(ws + 56 * MB);  // 16MB fp32
  bf16* h1  = (bf16*)(ws + 72 * MB);   // 32MB
  bf16* attn = x1;
  bf16* x2   = Qb;

  const dim3 TB(256);

  // weight transposes (src [R][C] -> dst [C][R])
  transpose_cast<<<dim3(32, 32), TB, 0, stream>>>(wq, wTq, 1024, 1024);
  transpose_cast<<<dim3(32, 32), TB, 0, stream>>>(wk, wTk, 1024, 1024);
  transpose_cast<<<dim3(32, 32), TB, 0, stream>>>(wv, wTv, 1024, 1024);
  transpose_cast<<<dim3(32, 32), TB, 0, stream>>>(wo, wTo, 1024, 1024);
  transpose_cast<<<dim3(128, 32), TB, 0, stream>>>(w1, wT1, 1024, 4096);
  transpose_cast<<<dim3(32, 128), TB, 0, stream>>>(w2, wT2, 4096, 1024);

  // LN1
  ln_kernel<<<1024, TB, 0, stream>>>(x, ln1_g, ln1_b, x1);

  // QKV projections
  gemm_bt<0><<<dim3(32, 8), TB, 0, stream>>>(x1, wTq, Qb, nullptr, nullptr, 4096, 1024, 1024);
  gemm_bt<0><<<dim3(32, 8), TB, 0, stream>>>(x1, wTk, Kb, nullptr, nullptr, 4096, 1024, 1024);
  gemm_bt<0><<<dim3(32, 8), TB, 0, stream>>>(x1, wTv, Vb, nullptr, nullptr, 4096, 1024, 1024);

  // attention
  attn_kernel<<<dim3(16, 64), TB, 0, stream>>>(Qb, Kb, Vb, attn);

  // O projection + residual -> xres (fp32)
  gemm_bt<1><<<dim3(32, 8), TB, 0, stream>>>(attn, wTo, xres, nullptr, x, 4096, 1024, 1024);

  // LN2
  ln_kernel<<<1024, TB, 0, stream>>>(xres, ln2_g, ln2_b, x2);

  // FFN1: relu(x2 @ w1 + b1) -> bf16
  gemm_bt<2><<<dim3(32, 32), TB, 0, stream>>>(x2, wT1, h1, b1, nullptr, 4096, 4096, 1024);

  // FFN2: h1 @ w2 + b2 + xres -> d_out (fp32)
  gemm_bt<1><<<dim3(32, 8), TB, 0, stream>>>(h1, wT2, (float*)d_out, b2, xres, 4096, 1024, 4096);
}

// Round 2
// 308.757 us; speedup vs baseline: 1.3665x; 1.3665x over previous
//
#include <hip/hip_runtime.h>

typedef __bf16 bf16;
typedef __bf16 bf16x8 __attribute__((ext_vector_type(8)));
typedef __bf16 bf16x4 __attribute__((ext_vector_type(4)));
typedef float f32x4 __attribute__((ext_vector_type(4)));

__device__ __forceinline__ void gload_lds16(const void* g, void* l) {
  __builtin_amdgcn_global_load_lds(
      (const __attribute__((address_space(1))) unsigned int*)g,
      (__attribute__((address_space(3))) unsigned int*)l, 16, 0, 0);
}

// ---------------- transpose + cast: src fp32 [R][C] -> dst bf16 [C][R] ----------------
__global__ __launch_bounds__(256) void transpose_cast(const float* __restrict__ src,
                                                      bf16* __restrict__ dst,
                                                      int R, int C) {
  __shared__ float tile[32][33];
  const int tx = threadIdx.x & 31, ty = threadIdx.x >> 5;  // 32 x 8
  const int c0 = blockIdx.x * 32, r0 = blockIdx.y * 32;
#pragma unroll
  for (int i = 0; i < 4; i++)
    tile[ty + i * 8][tx] = src[(size_t)(r0 + ty + i * 8) * C + c0 + tx];
  __syncthreads();
#pragma unroll
  for (int i = 0; i < 4; i++)
    dst[(size_t)(c0 + ty + i * 8) * R + r0 + tx] = (bf16)tile[tx][ty + i * 8];
}

// ---------------- LayerNorm: fp32 [rows][1024] -> bf16, 1 wave per row ----------------
__global__ __launch_bounds__(256) void ln_kernel(const float* __restrict__ x,
                                                 const float* __restrict__ g,
                                                 const float* __restrict__ b,
                                                 bf16* __restrict__ y) {
  const int w = threadIdx.x >> 6, lane = threadIdx.x & 63;
  const int row = blockIdx.x * 4 + w;
  const float* xr = x + (size_t)row * 1024;
  float4 v[4];
  float s = 0.f, sq = 0.f;
#pragma unroll
  for (int c = 0; c < 4; c++) {
    v[c] = *reinterpret_cast<const float4*>(xr + c * 256 + lane * 4);
    s += v[c].x + v[c].y + v[c].z + v[c].w;
    sq += v[c].x * v[c].x + v[c].y * v[c].y + v[c].z * v[c].z + v[c].w * v[c].w;
  }
#pragma unroll
  for (int d = 32; d >= 1; d >>= 1) {
    s += __shfl_xor(s, d, 64);
    sq += __shfl_xor(sq, d, 64);
  }
  const float mu = s * (1.f / 1024.f);
  const float rs = rsqrtf(sq * (1.f / 1024.f) - mu * mu + 1e-6f);
#pragma unroll
  for (int c = 0; c < 4; c++) {
    float4 gv = *reinterpret_cast<const float4*>(g + c * 256 + lane * 4);
    float4 bv = *reinterpret_cast<const float4*>(b + c * 256 + lane * 4);
    bf16x4 ov;
    ov[0] = (bf16)((v[c].x - mu) * rs * gv.x + bv.x);
    ov[1] = (bf16)((v[c].y - mu) * rs * gv.y + bv.y);
    ov[2] = (bf16)((v[c].z - mu) * rs * gv.z + bv.z);
    ov[3] = (bf16)((v[c].w - mu) * rs * gv.w + bv.w);
    *reinterpret_cast<bf16x4*>(y + (size_t)row * 1024 + c * 256 + lane * 4) = ov;
  }
}

// ---------------- GEMM: C[M][N] = A[M][K] @ Bt[N][K]^T, bf16 in, fp32 acc --------------
template <int EPI>
__global__ __launch_bounds__(256) void gemm_bt(const bf16* __restrict__ A,
                                               const bf16* __restrict__ Bt,
                                               void* __restrict__ Cout,
                                               const float* __restrict__ bias,
                                               const float* __restrict__ res,
                                               int M, int N, int K) {
  __shared__ __align__(16) bf16 As[128][32];
  __shared__ __align__(16) bf16 Bs[128][32];
  const int tid = threadIdx.x;
  const int w = tid >> 6, lane = tid & 63;
  const int wr = w >> 1, wc = w & 1;
  const int bm = blockIdx.x * 128, bn = blockIdx.y * 128;

  f32x4 acc[4][4] = {};
  const int r4 = lane >> 2;
  const int c8 = (lane & 3) * 8;
  const bf16* Ag = A + (size_t)(bm + w * 32 + r4) * K + c8;
  const bf16* Bg = Bt + (size_t)(bn + w * 32 + r4) * K + c8;
  const int fr = lane & 15, fo = (lane >> 4) * 8;

  for (int k0 = 0; k0 < K; k0 += 32) {
    gload_lds16(Ag + k0, &As[w * 32][0]);
    gload_lds16(Ag + (size_t)16 * K + k0, &As[w * 32 + 16][0]);
    gload_lds16(Bg + k0, &Bs[w * 32][0]);
    gload_lds16(Bg + (size_t)16 * K + k0, &Bs[w * 32 + 16][0]);
    __syncthreads();
    bf16x8 af[4], bfr[4];
#pragma unroll
    for (int m = 0; m < 4; m++) af[m] = *reinterpret_cast<const bf16x8*>(&As[wr * 64 + m * 16 + fr][fo]);
#pragma unroll
    for (int n = 0; n < 4; n++) bfr[n] = *reinterpret_cast<const bf16x8*>(&Bs[wc * 64 + n * 16 + fr][fo]);
#pragma unroll
    for (int m = 0; m < 4; m++)
#pragma unroll
      for (int n = 0; n < 4; n++)
        acc[m][n] = __builtin_amdgcn_mfma_f32_16x16x32_bf16(af[m], bfr[n], acc[m][n], 0, 0, 0);
    __syncthreads();
  }

  const int cr = (lane >> 4) * 4, cc = lane & 15;
#pragma unroll
  for (int m = 0; m < 4; m++) {
#pragma unroll
    for (int n = 0; n < 4; n++) {
      const int row = bm + wr * 64 + m * 16 + cr;
      const int col = bn + wc * 64 + n * 16 + cc;
#pragma unroll
      for (int r = 0; r < 4; r++) {
        const float va = acc[m][n][r];
        const size_t idx = (size_t)(row + r) * N + col;
        if (EPI == 0) {
          ((bf16*)Cout)[idx] = (bf16)va;
        } else if (EPI == 1) {
          ((float*)Cout)[idx] = va + (bias ? bias[col] : 0.f) + res[idx];
        } else {
          const float t = va + bias[col];
          ((bf16*)Cout)[idx] = (bf16)(t > 0.f ? t : 0.f);
        }
      }
    }
  }
}

// ---------------- Flash attention v2: swapped QK^T, KVBLK=64, 32q/wave ----------------
// grid: 512 = (bh 64) x (qblock 8); block 256 (4 waves); ld = row stride of Q/K/V
__global__ __launch_bounds__(256) void attn_kernel(const bf16* __restrict__ Q,
                                                   const bf16* __restrict__ K,
                                                   const bf16* __restrict__ V,
                                                   bf16* __restrict__ O, int ld) {
  __shared__ __align__(16) bf16 Ks[2][64][64];
  __shared__ __align__(16) bf16 Vt[2][64][64];
  __shared__ __align__(16) bf16 Pl[4][32][64];
  const int tid = threadIdx.x;
  const int w = tid >> 6, l = tid & 63;
  const int lo = l & 15, g = l >> 4;
  const int sw = (lo & 7) << 3;

  const int id = blockIdx.x;
  const int bh = id & 63, qb = id >> 6;  // same-bh blocks land on same XCD
  const int b = bh >> 4, h = bh & 15;
  const int hoff = h * 64;
  const size_t rowQ = (size_t)b * 1024 + qb * 128 + w * 32;
  const size_t rowKV0 = (size_t)b * 1024;

  // Q fragments (B-operand: n = q-row, k = d)
  bf16x8 qfr[2][2];
#pragma unroll
  for (int qi = 0; qi < 2; qi++)
#pragma unroll
    for (int ds = 0; ds < 2; ds++)
      qfr[qi][ds] = *reinterpret_cast<const bf16x8*>(
          Q + (rowQ + qi * 16 + lo) * ld + hoff + ds * 32 + g * 8);

  const float c = 0.18033688f;  // 0.125 * log2(e)
  float m[2] = {-1e30f, -1e30f}, lsum[2] = {0.f, 0.f};
  f32x4 o[4][2] = {};

  // prologue: stage tile 0 into buf 0
  {
#pragma unroll
    for (int i = 0; i < 2; i++) {
      const int idx = tid + i * 256;
      const int row = idx >> 3, cch = idx & 7;
      gload_lds16(K + (rowKV0 + row) * ld + hoff + ((cch ^ (row & 7)) << 3),
                  &Ks[0][row][cch << 3]);
    }
    const bf16* vp = V + (rowKV0 + l) * ld + hoff + w * 16;
    bf16x8 va = *reinterpret_cast<const bf16x8*>(vp);
    bf16x8 vb = *reinterpret_cast<const bf16x8*>(vp + 8);
#pragma unroll
    for (int j = 0; j < 8; j++) Vt[0][w * 16 + j][l ^ (j << 3)] = va[j];
#pragma unroll
    for (int j = 0; j < 8; j++) Vt[0][w * 16 + 8 + j][l ^ (j << 3)] = vb[j];
  }
  __syncthreads();

  int bb = 0;
  for (int kt = 0; kt < 16; kt++) {
    bf16x8 va, vb;
    const bool more = (kt + 1) < 16;
    if (more) {  // issue next-tile loads before compute (latency hides under MFMA)
      const size_t rkv = rowKV0 + (kt + 1) * 64;
#pragma unroll
      for (int i = 0; i < 2; i++) {
        const int idx = tid + i * 256;
        const int row = idx >> 3, cch = idx & 7;
        gload_lds16(K + (rkv + row) * ld + hoff + ((cch ^ (row & 7)) << 3),
                    &Ks[bb ^ 1][row][cch << 3]);
      }
      const bf16* vp = V + (rkv + l) * ld + hoff + w * 16;
      va = *reinterpret_cast<const bf16x8*>(vp);
      vb = *reinterpret_cast<const bf16x8*>(vp + 8);
    }

    // ---- QK^T (swapped): S^T[key][q], lane: q = lo(+16qi), key = 16*kf + 4g + r
    f32x4 sa[4][2] = {};
#pragma unroll
    for (int ds = 0; ds < 2; ds++) {
      bf16x8 kf[4];
#pragma unroll
      for (int kfi = 0; kfi < 4; kfi++)
        kf[kfi] = *reinterpret_cast<const bf16x8*>(&Ks[bb][kfi * 16 + lo][(ds * 32 + g * 8) ^ sw]);
#pragma unroll
      for (int kfi = 0; kfi < 4; kfi++)
#pragma unroll
        for (int qi = 0; qi < 2; qi++)
          sa[kfi][qi] = __builtin_amdgcn_mfma_f32_16x16x32_bf16(kf[kfi], qfr[qi][ds], sa[kfi][qi], 0, 0, 0);
    }

    // ---- online softmax (raw-scores; scale folded into exp2 arg)
#pragma unroll
    for (int qi = 0; qi < 2; qi++) {
      float m0 = fmaxf(fmaxf(sa[0][qi][0], sa[0][qi][1]), fmaxf(sa[0][qi][2], sa[0][qi][3]));
      float m1 = fmaxf(fmaxf(sa[1][qi][0], sa[1][qi][1]), fmaxf(sa[1][qi][2], sa[1][qi][3]));
      float m2 = fmaxf(fmaxf(sa[2][qi][0], sa[2][qi][1]), fmaxf(sa[2][qi][2], sa[2][qi][3]));
      float m3 = fmaxf(fmaxf(sa[3][qi][0], sa[3][qi][1]), fmaxf(sa[3][qi][2], sa[3][qi][3]));
      float mx = fmaxf(fmaxf(m0, m1), fmaxf(m2, m3));
      mx = fmaxf(mx, __shfl_xor(mx, 16));
      mx = fmaxf(mx, __shfl_xor(mx, 32));
      const float mn = fmaxf(m[qi], mx);
      const float sc = exp2f((m[qi] - mn) * c);
      const float mc = mn * c;
      m[qi] = mn;
      float p[16];
#pragma unroll
      for (int kfi = 0; kfi < 4; kfi++)
#pragma unroll
        for (int r = 0; r < 4; r++)
          p[kfi * 4 + r] = exp2f(fmaf(sa[kfi][qi][r], c, -mc));
      float s0 = (p[0] + p[1]) + (p[2] + p[3]);
      float s1 = (p[4] + p[5]) + (p[6] + p[7]);
      float s2 = (p[8] + p[9]) + (p[10] + p[11]);
      float s3 = (p[12] + p[13]) + (p[14] + p[15]);
      float sum = (s0 + s1) + (s2 + s3);
      sum += __shfl_xor(sum, 16);
      sum += __shfl_xor(sum, 32);
      lsum[qi] = lsum[qi] * sc + sum;
#pragma unroll
      for (int df = 0; df < 4; df++)
#pragma unroll
        for (int r = 0; r < 4; r++) o[df][qi][r] *= sc;
      // pack P -> per-wave LDS rows [q][k] (swizzled)
#pragma unroll
      for (int kfi = 0; kfi < 4; kfi++) {
        bf16x4 pk;
        pk[0] = (bf16)p[kfi * 4 + 0];
        pk[1] = (bf16)p[kfi * 4 + 1];
        pk[2] = (bf16)p[kfi * 4 + 2];
        pk[3] = (bf16)p[kfi * 4 + 3];
        *reinterpret_cast<bf16x4*>(&Pl[w][qi * 16 + lo][(kfi * 16 + g * 4) ^ sw]) = pk;
      }
    }

    // ---- PV (swapped): O^T[d][q] += V^T[d][k] P^T[k][q]
#pragma unroll
    for (int ks = 0; ks < 2; ks++) {
      bf16x8 pf[2], vf[4];
#pragma unroll
      for (int qi = 0; qi < 2; qi++)
        pf[qi] = *reinterpret_cast<const bf16x8*>(&Pl[w][qi * 16 + lo][(ks * 32 + g * 8) ^ sw]);
#pragma unroll
      for (int df = 0; df < 4; df++)
        vf[df] = *reinterpret_cast<const bf16x8*>(&Vt[bb][df * 16 + lo][(ks * 32 + g * 8) ^ sw]);
#pragma unroll
      for (int df = 0; df < 4; df++)
#pragma unroll
        for (int qi = 0; qi < 2; qi++)
          o[df][qi] = __builtin_amdgcn_mfma_f32_16x16x32_bf16(vf[df], pf[qi], o[df][qi], 0, 0, 0);
    }

    if (more) {  // V scatter for next tile (loads have drained under compute)
#pragma unroll
      for (int j = 0; j < 8; j++) Vt[bb ^ 1][w * 16 + j][l ^ (j << 3)] = va[j];
#pragma unroll
      for (int j = 0; j < 8; j++) Vt[bb ^ 1][w * 16 + 8 + j][l ^ (j << 3)] = vb[j];
    }
    __syncthreads();
    bb ^= 1;
  }

  // epilogue: O^T regs -> per-wave LDS (reuse Pl) -> coalesced global O[q][d]
#pragma unroll
  for (int qi = 0; qi < 2; qi++) {
    const float rl = 1.f / lsum[qi];
#pragma unroll
    for (int df = 0; df < 4; df++) {
      bf16x4 ov;
#pragma unroll
      for (int r = 0; r < 4; r++) ov[r] = (bf16)(o[df][qi][r] * rl);
      *reinterpret_cast<bf16x4*>(&Pl[w][qi * 16 + lo][(df * 16 + g * 4) ^ sw]) = ov;
    }
  }
  const int row = l >> 1;
  const int swr = (row & 7) << 3;
#pragma unroll
  for (int i = 0; i < 4; i++) {
    const int c2 = (l & 1) * 4 + i;
    bf16x8 ov = *reinterpret_cast<const bf16x8*>(&Pl[w][row][(c2 * 8) ^ swr]);
    *reinterpret_cast<bf16x8*>(O + (rowQ + row) * 1024 + hoff + c2 * 8) = ov;
  }
}

// --------------------------------- launch -------------------------------------------
extern "C" void kernel_launch(void* const* d_in, const int* in_sizes, int n_in,
                              void* d_out, int out_size, void* d_ws, size_t ws_size,
                              hipStream_t stream) {
  const float* x     = (const float*)d_in[0];
  const float* ln1_g = (const float*)d_in[1];
  const float* ln1_b = (const float*)d_in[2];
  const float* wq    = (const float*)d_in[3];
  const float* wk    = (const float*)d_in[4];
  const float* wv    = (const float*)d_in[5];
  const float* wo    = (const float*)d_in[6];
  const float* ln2_g = (const float*)d_in[7];
  const float* ln2_b = (const float*)d_in[8];
  const float* w1    = (const float*)d_in[9];
  const float* b1    = (const float*)d_in[10];
  const float* w2    = (const float*)d_in[11];
  const float* b2    = (const float*)d_in[12];

  const size_t MB = 1ull << 20;
  char* ws = (char*)d_ws;
  bf16* wTqkv = (bf16*)(ws + 0 * MB);    // [3072][1024] bf16 = 6MB
  bf16* wTo   = (bf16*)(ws + 6 * MB);    // 2MB
  bf16* wT1   = (bf16*)(ws + 8 * MB);    // 8MB
  bf16* wT2   = (bf16*)(ws + 16 * MB);   // 8MB
  bf16* x1    = (bf16*)(ws + 24 * MB);   // 8MB; attn output aliases later
  bf16* qkv   = (bf16*)(ws + 32 * MB);   // [4096][3072] bf16 = 24MB; x2 aliases later
  float* xres = (float*)(ws + 56 * MB);  // 16MB fp32
  bf16* h1    = (bf16*)(ws + 72 * MB);   // 32MB
  bf16* attn  = x1;
  bf16* x2    = qkv;

  const dim3 TB(256);

  // weight transposes (src [R][C] -> dst [C][R]); QKV into one contiguous [3072][1024]
  transpose_cast<<<dim3(32, 32), TB, 0, stream>>>(wq, wTqkv, 1024, 1024);
  transpose_cast<<<dim3(32, 32), TB, 0, stream>>>(wk, wTqkv + 1024 * 1024, 1024, 1024);
  transpose_cast<<<dim3(32, 32), TB, 0, stream>>>(wv, wTqkv + 2048 * 1024, 1024, 1024);
  transpose_cast<<<dim3(32, 32), TB, 0, stream>>>(wo, wTo, 1024, 1024);
  transpose_cast<<<dim3(128, 32), TB, 0, stream>>>(w1, wT1, 1024, 4096);
  transpose_cast<<<dim3(32, 128), TB, 0, stream>>>(w2, wT2, 4096, 1024);

  // LN1
  ln_kernel<<<1024, TB, 0, stream>>>(x, ln1_g, ln1_b, x1);

  // fused QKV projection: [4096][1024] @ [1024][3072] -> [4096][3072]
  gemm_bt<0><<<dim3(32, 24), TB, 0, stream>>>(x1, wTqkv, qkv, nullptr, nullptr, 4096, 3072, 1024);

  // attention (Q/K/V interleaved, row stride 3072)
  attn_kernel<<<512, TB, 0, stream>>>(qkv, qkv + 1024, qkv + 2048, attn, 3072);

  // O projection + residual -> xres (fp32)
  gemm_bt<1><<<dim3(32, 8), TB, 0, stream>>>(attn, wTo, xres, nullptr, x, 4096, 1024, 1024);

  // LN2
  ln_kernel<<<1024, TB, 0, stream>>>(xres, ln2_g, ln2_b, x2);

  // FFN1: relu(x2 @ w1 + b1) -> bf16
  gemm_bt<2><<<dim3(32, 32), TB, 0, stream>>>(x2, wT1, h1, b1, nullptr, 4096, 4096, 1024);

  // FFN2: h1 @ w2 + b2 + xres -> d_out (fp32)
  gemm_bt<1><<<dim3(32, 8), TB, 0, stream>>>(h1, wT2, (float*)d_out, b2, xres, 4096, 1024, 4096);
}

// Round 3
// 293.874 us; speedup vs baseline: 1.4357x; 1.0506x over previous
//
#include <hip/hip_runtime.h>

typedef __bf16 bf16;
typedef __bf16 bf16x8 __attribute__((ext_vector_type(8)));
typedef __bf16 bf16x4 __attribute__((ext_vector_type(4)));
typedef float f32x4 __attribute__((ext_vector_type(4)));

__device__ __forceinline__ void gload_lds16(const void* g, void* l) {
  __builtin_amdgcn_global_load_lds(
      (const __attribute__((address_space(1))) unsigned int*)g,
      (__attribute__((address_space(3))) unsigned int*)l, 16, 0, 0);
}

// ---------------- transpose + cast: src fp32 [R][C] -> dst bf16 [C][R] ----------------
__global__ __launch_bounds__(256) void transpose_cast(const float* __restrict__ src,
                                                      bf16* __restrict__ dst,
                                                      int R, int C) {
  __shared__ float tile[32][33];
  const int tx = threadIdx.x & 31, ty = threadIdx.x >> 5;  // 32 x 8
  const int c0 = blockIdx.x * 32, r0 = blockIdx.y * 32;
#pragma unroll
  for (int i = 0; i < 4; i++)
    tile[ty + i * 8][tx] = src[(size_t)(r0 + ty + i * 8) * C + c0 + tx];
  __syncthreads();
#pragma unroll
  for (int i = 0; i < 4; i++)
    dst[(size_t)(c0 + ty + i * 8) * R + r0 + tx] = (bf16)tile[tx][ty + i * 8];
}

// ---------------- LayerNorm: fp32 [rows][1024] -> bf16, 1 wave per row ----------------
__global__ __launch_bounds__(256) void ln_kernel(const float* __restrict__ x,
                                                 const float* __restrict__ g,
                                                 const float* __restrict__ b,
                                                 bf16* __restrict__ y) {
  const int w = threadIdx.x >> 6, lane = threadIdx.x & 63;
  const int row = blockIdx.x * 4 + w;
  const float* xr = x + (size_t)row * 1024;
  float4 v[4];
  float s = 0.f, sq = 0.f;
#pragma unroll
  for (int c = 0; c < 4; c++) {
    v[c] = *reinterpret_cast<const float4*>(xr + c * 256 + lane * 4);
    s += v[c].x + v[c].y + v[c].z + v[c].w;
    sq += v[c].x * v[c].x + v[c].y * v[c].y + v[c].z * v[c].z + v[c].w * v[c].w;
  }
#pragma unroll
  for (int d = 32; d >= 1; d >>= 1) {
    s += __shfl_xor(s, d, 64);
    sq += __shfl_xor(sq, d, 64);
  }
  const float mu = s * (1.f / 1024.f);
  const float rs = rsqrtf(sq * (1.f / 1024.f) - mu * mu + 1e-6f);
#pragma unroll
  for (int c = 0; c < 4; c++) {
    float4 gv = *reinterpret_cast<const float4*>(g + c * 256 + lane * 4);
    float4 bv = *reinterpret_cast<const float4*>(b + c * 256 + lane * 4);
    bf16x4 ov;
    ov[0] = (bf16)((v[c].x - mu) * rs * gv.x + bv.x);
    ov[1] = (bf16)((v[c].y - mu) * rs * gv.y + bv.y);
    ov[2] = (bf16)((v[c].z - mu) * rs * gv.z + bv.z);
    ov[3] = (bf16)((v[c].w - mu) * rs * gv.w + bv.w);
    *reinterpret_cast<bf16x4*>(y + (size_t)row * 1024 + c * 256 + lane * 4) = ov;
  }
}

// ---------------- GEMM: C[M][N] = A[M][K] @ Bt[N][K]^T, bf16 in, fp32 acc --------------
// 2-phase double-buffered pipeline: STAGE(t+1) issued before compute(t); one
// vmcnt(0)+barrier per K-step (emitted by __syncthreads). 1-D grid, XCD swizzle.
template <int EPI>
__global__ __launch_bounds__(256) void gemm_bt(const bf16* __restrict__ A,
                                               const bf16* __restrict__ Bt,
                                               void* __restrict__ Cout,
                                               const float* __restrict__ bias,
                                               const float* __restrict__ res,
                                               int M, int N, int K, int gy) {
  __shared__ __align__(16) bf16 As[2][128][32];
  __shared__ __align__(16) bf16 Bs[2][128][32];
  const int tid = threadIdx.x;
  const int w = tid >> 6, lane = tid & 63;
  const int wr = w >> 1, wc = w & 1;

  // XCD-aware bijective swizzle (all launch grids are multiples of 8)
  const int nwg = gridDim.x;
  const int cpx = nwg >> 3;
  const int swz = (blockIdx.x & 7) * cpx + (blockIdx.x >> 3);
  const int bm = (swz / gy) * 128, bn = (swz % gy) * 128;

  f32x4 acc[4][4] = {};
  const int r4 = lane >> 2;        // 0..15
  const int c8 = (lane & 3) * 8;   // k offset within 32
  const bf16* Ag = A + (size_t)(bm + w * 32 + r4) * K + c8;
  const bf16* Bg = Bt + (size_t)(bn + w * 32 + r4) * K + c8;
  const int fr = lane & 15, fo = (lane >> 4) * 8;

#define STAGE(buf, k0)                                              \
  do {                                                              \
    gload_lds16(Ag + (k0), &As[buf][w * 32][0]);                    \
    gload_lds16(Ag + (size_t)16 * K + (k0), &As[buf][w * 32 + 16][0]); \
    gload_lds16(Bg + (k0), &Bs[buf][w * 32][0]);                    \
    gload_lds16(Bg + (size_t)16 * K + (k0), &Bs[buf][w * 32 + 16][0]); \
  } while (0)

  const int nt = K >> 5;
  STAGE(0, 0);
  __syncthreads();
  int cur = 0;
  for (int t = 0; t < nt; ++t) {
    if (t + 1 < nt) STAGE(cur ^ 1, (t + 1) << 5);  // prefetch overlaps compute
    bf16x8 af[4], bfr[4];
#pragma unroll
    for (int m = 0; m < 4; m++)
      af[m] = *reinterpret_cast<const bf16x8*>(&As[cur][wr * 64 + m * 16 + fr][fo]);
#pragma unroll
    for (int n = 0; n < 4; n++)
      bfr[n] = *reinterpret_cast<const bf16x8*>(&Bs[cur][wc * 64 + n * 16 + fr][fo]);
#pragma unroll
    for (int m = 0; m < 4; m++)
#pragma unroll
      for (int n = 0; n < 4; n++)
        acc[m][n] = __builtin_amdgcn_mfma_f32_16x16x32_bf16(af[m], bfr[n], acc[m][n], 0, 0, 0);
    __syncthreads();  // drains prefetch (vmcnt 0) + all waves done reading cur
    cur ^= 1;
  }
#undef STAGE

  const int cr = (lane >> 4) * 4, cc = lane & 15;
#pragma unroll
  for (int m = 0; m < 4; m++) {
#pragma unroll
    for (int n = 0; n < 4; n++) {
      const int row = bm + wr * 64 + m * 16 + cr;
      const int col = bn + wc * 64 + n * 16 + cc;
#pragma unroll
      for (int r = 0; r < 4; r++) {
        const float va = acc[m][n][r];
        const size_t idx = (size_t)(row + r) * N + col;
        if (EPI == 0) {
          ((bf16*)Cout)[idx] = (bf16)va;
        } else if (EPI == 1) {
          ((float*)Cout)[idx] = va + (bias ? bias[col] : 0.f) + res[idx];
        } else {
          const float t = va + bias[col];
          ((bf16*)Cout)[idx] = (bf16)(t > 0.f ? t : 0.f);
        }
      }
    }
  }
}

// ---------------- Flash attention v2: swapped QK^T, KVBLK=64, 32q/wave ----------------
__global__ __launch_bounds__(256) void attn_kernel(const bf16* __restrict__ Q,
                                                   const bf16* __restrict__ K,
                                                   const bf16* __restrict__ V,
                                                   bf16* __restrict__ O, int ld) {
  __shared__ __align__(16) bf16 Ks[2][64][64];
  __shared__ __align__(16) bf16 Vt[2][64][64];
  __shared__ __align__(16) bf16 Pl[4][32][64];
  const int tid = threadIdx.x;
  const int w = tid >> 6, l = tid & 63;
  const int lo = l & 15, g = l >> 4;
  const int sw = (lo & 7) << 3;

  const int id = blockIdx.x;
  const int bh = id & 63, qb = id >> 6;
  const int b = bh >> 4, h = bh & 15;
  const int hoff = h * 64;
  const size_t rowQ = (size_t)b * 1024 + qb * 128 + w * 32;
  const size_t rowKV0 = (size_t)b * 1024;

  bf16x8 qfr[2][2];
#pragma unroll
  for (int qi = 0; qi < 2; qi++)
#pragma unroll
    for (int ds = 0; ds < 2; ds++)
      qfr[qi][ds] = *reinterpret_cast<const bf16x8*>(
          Q + (rowQ + qi * 16 + lo) * ld + hoff + ds * 32 + g * 8);

  const float c = 0.18033688f;  // 0.125 * log2(e)
  float m[2] = {-1e30f, -1e30f}, lsum[2] = {0.f, 0.f};
  f32x4 o[4][2] = {};

  {
#pragma unroll
    for (int i = 0; i < 2; i++) {
      const int idx = tid + i * 256;
      const int row = idx >> 3, cch = idx & 7;
      gload_lds16(K + (rowKV0 + row) * ld + hoff + ((cch ^ (row & 7)) << 3),
                  &Ks[0][row][cch << 3]);
    }
    const bf16* vp = V + (rowKV0 + l) * ld + hoff + w * 16;
    bf16x8 va = *reinterpret_cast<const bf16x8*>(vp);
    bf16x8 vb = *reinterpret_cast<const bf16x8*>(vp + 8);
#pragma unroll
    for (int j = 0; j < 8; j++) Vt[0][w * 16 + j][l ^ (j << 3)] = va[j];
#pragma unroll
    for (int j = 0; j < 8; j++) Vt[0][w * 16 + 8 + j][l ^ (j << 3)] = vb[j];
  }
  __syncthreads();

  int bb = 0;
  for (int kt = 0; kt < 16; kt++) {
    bf16x8 va, vb;
    const bool more = (kt + 1) < 16;
    if (more) {
      const size_t rkv = rowKV0 + (kt + 1) * 64;
#pragma unroll
      for (int i = 0; i < 2; i++) {
        const int idx = tid + i * 256;
        const int row = idx >> 3, cch = idx & 7;
        gload_lds16(K + (rkv + row) * ld + hoff + ((cch ^ (row & 7)) << 3),
                    &Ks[bb ^ 1][row][cch << 3]);
      }
      const bf16* vp = V + (rkv + l) * ld + hoff + w * 16;
      va = *reinterpret_cast<const bf16x8*>(vp);
      vb = *reinterpret_cast<const bf16x8*>(vp + 8);
    }

    f32x4 sa[4][2] = {};
#pragma unroll
    for (int ds = 0; ds < 2; ds++) {
      bf16x8 kf[4];
#pragma unroll
      for (int kfi = 0; kfi < 4; kfi++)
        kf[kfi] = *reinterpret_cast<const bf16x8*>(&Ks[bb][kfi * 16 + lo][(ds * 32 + g * 8) ^ sw]);
#pragma unroll
      for (int kfi = 0; kfi < 4; kfi++)
#pragma unroll
        for (int qi = 0; qi < 2; qi++)
          sa[kfi][qi] = __builtin_amdgcn_mfma_f32_16x16x32_bf16(kf[kfi], qfr[qi][ds], sa[kfi][qi], 0, 0, 0);
    }

#pragma unroll
    for (int qi = 0; qi < 2; qi++) {
      float m0 = fmaxf(fmaxf(sa[0][qi][0], sa[0][qi][1]), fmaxf(sa[0][qi][2], sa[0][qi][3]));
      float m1 = fmaxf(fmaxf(sa[1][qi][0], sa[1][qi][1]), fmaxf(sa[1][qi][2], sa[1][qi][3]));
      float m2 = fmaxf(fmaxf(sa[2][qi][0], sa[2][qi][1]), fmaxf(sa[2][qi][2], sa[2][qi][3]));
      float m3 = fmaxf(fmaxf(sa[3][qi][0], sa[3][qi][1]), fmaxf(sa[3][qi][2], sa[3][qi][3]));
      float mx = fmaxf(fmaxf(m0, m1), fmaxf(m2, m3));
      mx = fmaxf(mx, __shfl_xor(mx, 16));
      mx = fmaxf(mx, __shfl_xor(mx, 32));
      const float mn = fmaxf(m[qi], mx);
      const float sc = exp2f((m[qi] - mn) * c);
      const float mc = mn * c;
      m[qi] = mn;
      float p[16];
#pragma unroll
      for (int kfi = 0; kfi < 4; kfi++)
#pragma unroll
        for (int r = 0; r < 4; r++)
          p[kfi * 4 + r] = exp2f(fmaf(sa[kfi][qi][r], c, -mc));
      float s0 = (p[0] + p[1]) + (p[2] + p[3]);
      float s1 = (p[4] + p[5]) + (p[6] + p[7]);
      float s2 = (p[8] + p[9]) + (p[10] + p[11]);
      float s3 = (p[12] + p[13]) + (p[14] + p[15]);
      float sum = (s0 + s1) + (s2 + s3);
      sum += __shfl_xor(sum, 16);
      sum += __shfl_xor(sum, 32);
      lsum[qi] = lsum[qi] * sc + sum;
#pragma unroll
      for (int df = 0; df < 4; df++)
#pragma unroll
        for (int r = 0; r < 4; r++) o[df][qi][r] *= sc;
#pragma unroll
      for (int kfi = 0; kfi < 4; kfi++) {
        bf16x4 pk;
        pk[0] = (bf16)p[kfi * 4 + 0];
        pk[1] = (bf16)p[kfi * 4 + 1];
        pk[2] = (bf16)p[kfi * 4 + 2];
        pk[3] = (bf16)p[kfi * 4 + 3];
        *reinterpret_cast<bf16x4*>(&Pl[w][qi * 16 + lo][(kfi * 16 + g * 4) ^ sw]) = pk;
      }
    }

#pragma unroll
    for (int ks = 0; ks < 2; ks++) {
      bf16x8 pf[2], vf[4];
#pragma unroll
      for (int qi = 0; qi < 2; qi++)
        pf[qi] = *reinterpret_cast<const bf16x8*>(&Pl[w][qi * 16 + lo][(ks * 32 + g * 8) ^ sw]);
#pragma unroll
      for (int df = 0; df < 4; df++)
        vf[df] = *reinterpret_cast<const bf16x8*>(&Vt[bb][df * 16 + lo][(ks * 32 + g * 8) ^ sw]);
#pragma unroll
      for (int df = 0; df < 4; df++)
#pragma unroll
        for (int qi = 0; qi < 2; qi++)
          o[df][qi] = __builtin_amdgcn_mfma_f32_16x16x32_bf16(vf[df], pf[qi], o[df][qi], 0, 0, 0);
    }

    if (more) {
#pragma unroll
      for (int j = 0; j < 8; j++) Vt[bb ^ 1][w * 16 + j][l ^ (j << 3)] = va[j];
#pragma unroll
      for (int j = 0; j < 8; j++) Vt[bb ^ 1][w * 16 + 8 + j][l ^ (j << 3)] = vb[j];
    }
    __syncthreads();
    bb ^= 1;
  }

#pragma unroll
  for (int qi = 0; qi < 2; qi++) {
    const float rl = 1.f / lsum[qi];
#pragma unroll
    for (int df = 0; df < 4; df++) {
      bf16x4 ov;
#pragma unroll
      for (int r = 0; r < 4; r++) ov[r] = (bf16)(o[df][qi][r] * rl);
      *reinterpret_cast<bf16x4*>(&Pl[w][qi * 16 + lo][(df * 16 + g * 4) ^ sw]) = ov;
    }
  }
  const int row = l >> 1;
  const int swr = (row & 7) << 3;
#pragma unroll
  for (int i = 0; i < 4; i++) {
    const int c2 = (l & 1) * 4 + i;
    bf16x8 ov = *reinterpret_cast<const bf16x8*>(&Pl[w][row][(c2 * 8) ^ swr]);
    *reinterpret_cast<bf16x8*>(O + (rowQ + row) * 1024 + hoff + c2 * 8) = ov;
  }
}

// --------------------------------- launch -------------------------------------------
extern "C" void kernel_launch(void* const* d_in, const int* in_sizes, int n_in,
                              void* d_out, int out_size, void* d_ws, size_t ws_size,
                              hipStream_t stream) {
  const float* x     = (const float*)d_in[0];
  const float* ln1_g = (const float*)d_in[1];
  const float* ln1_b = (const float*)d_in[2];
  const float* wq    = (const float*)d_in[3];
  const float* wk    = (const float*)d_in[4];
  const float* wv    = (const float*)d_in[5];
  const float* wo    = (const float*)d_in[6];
  const float* ln2_g = (const float*)d_in[7];
  const float* ln2_b = (const float*)d_in[8];
  const float* w1    = (const float*)d_in[9];
  const float* b1    = (const float*)d_in[10];
  const float* w2    = (const float*)d_in[11];
  const float* b2    = (const float*)d_in[12];

  const size_t MB = 1ull << 20;
  char* ws = (char*)d_ws;
  bf16* wTqkv = (bf16*)(ws + 0 * MB);    // [3072][1024] bf16 = 6MB
  bf16* wTo   = (bf16*)(ws + 6 * MB);    // 2MB
  bf16* wT1   = (bf16*)(ws + 8 * MB);    // 8MB
  bf16* wT2   = (bf16*)(ws + 16 * MB);   // 8MB
  bf16* x1    = (bf16*)(ws + 24 * MB);   // 8MB; attn output aliases later
  bf16* qkv   = (bf16*)(ws + 32 * MB);   // [4096][3072] bf16 = 24MB; x2 aliases later
  float* xres = (float*)(ws + 56 * MB);  // 16MB fp32
  bf16* h1    = (bf16*)(ws + 72 * MB);   // 32MB
  bf16* attn  = x1;
  bf16* x2    = qkv;

  const dim3 TB(256);

  transpose_cast<<<dim3(32, 32), TB, 0, stream>>>(wq, wTqkv, 1024, 1024);
  transpose_cast<<<dim3(32, 32), TB, 0, stream>>>(wk, wTqkv + 1024 * 1024, 1024, 1024);
  transpose_cast<<<dim3(32, 32), TB, 0, stream>>>(wv, wTqkv + 2048 * 1024, 1024, 1024);
  transpose_cast<<<dim3(32, 32), TB, 0, stream>>>(wo, wTo, 1024, 1024);
  transpose_cast<<<dim3(128, 32), TB, 0, stream>>>(w1, wT1, 1024, 4096);
  transpose_cast<<<dim3(32, 128), TB, 0, stream>>>(w2, wT2, 4096, 1024);

  ln_kernel<<<1024, TB, 0, stream>>>(x, ln1_g, ln1_b, x1);

  // fused QKV projection: [4096][1024] @ -> [4096][3072]; grid 32x24=768
  gemm_bt<0><<<768, TB, 0, stream>>>(x1, wTqkv, qkv, nullptr, nullptr, 4096, 3072, 1024, 24);

  attn_kernel<<<512, TB, 0, stream>>>(qkv, qkv + 1024, qkv + 2048, attn, 3072);

  // O projection + residual -> xres (fp32); grid 32x8=256
  gemm_bt<1><<<256, TB, 0, stream>>>(attn, wTo, xres, nullptr, x, 4096, 1024, 1024, 8);

  ln_kernel<<<1024, TB, 0, stream>>>(xres, ln2_g, ln2_b, x2);

  // FFN1: relu(x2 @ w1 + b1) -> bf16; grid 32x32=1024
  gemm_bt<2><<<1024, TB, 0, stream>>>(x2, wT1, h1, b1, nullptr, 4096, 4096, 1024, 32);

  // FFN2: h1 @ w2 + b2 + xres -> d_out (fp32); grid 32x8=256
  gemm_bt<1><<<256, TB, 0, stream>>>(h1, wT2, (float*)d_out, b2, xres, 4096, 1024, 4096, 8);
}